// Round 1
// baseline (351.438 us; speedup 1.0000x reference)
//
#include <hip/hip_runtime.h>
#include <hip/hip_bf16.h>

#define B_ 16
#define C_ 256
#define L_ 2048

typedef __attribute__((ext_vector_type(8))) short bf16x8;
typedef __attribute__((ext_vector_type(4))) float f32x4;

// round-to-nearest-even float -> bf16 (protects accuracy margin; HIP cast may truncate)
__device__ __forceinline__ short f2bf_rne(float f) {
    union { float f; unsigned u; } x; x.f = f;
    unsigned r = x.u + 0x7fffu + ((x.u >> 16) & 1u);
    return (short)(r >> 16);
}

// ---------------- prepass 1: (B,C,L) fp32 -> (B,L,C) bf16, for Q and K ----------------
// grid = 2 * 16 * 4 * 32 = 4096 blocks of 256 threads; 64x64 tile transpose through LDS.
__global__ __launch_bounds__(256) void transpose_cvt_kernel(
        const float* __restrict__ Qin, const float* __restrict__ Kin,
        short* __restrict__ Qt, short* __restrict__ Kt) {
    __shared__ unsigned short tile[64 * 65];   // [li][ci], stride 65 to spread banks
    const int bid = blockIdx.x;
    const int tens = bid >> 11;
    const int b  = (bid >> 7) & 15;
    const int cb = (bid >> 5) & 3;
    const int lb = bid & 31;
    const int c0 = cb * 64, l0 = lb * 64;
    const float* __restrict__ src = tens ? Kin : Qin;
    short* __restrict__ dst = tens ? Kt : Qt;
    const int t = threadIdx.x;
    const int w = t >> 6, lane = t & 63;
    #pragma unroll
    for (int i = 0; i < 16; ++i) {
        int ci = 4 * i + w;                                   // 0..63
        float v = src[((size_t)b * C_ + (c0 + ci)) * L_ + l0 + lane];  // coalesced in l
        tile[lane * 65 + ci] = (unsigned short)f2bf_rne(v);
    }
    __syncthreads();
    #pragma unroll
    for (int i = 0; i < 8; ++i) {
        int li = 8 * i + (t >> 5);                            // 0..63
        int cp = (t & 31) * 2;
        unsigned lo = tile[li * 65 + cp];
        unsigned hi = tile[li * 65 + cp + 1];
        *(unsigned*)(dst + ((size_t)b * L_ + (l0 + li)) * C_ + c0 + cp) = lo | (hi << 16);
    }
}

// ---------------- prepass 2: Vb[b][c][m] = bf16(V[b][c][m] * mask[b][m]) ----------------
// grid = 4096 blocks of 256 threads, 8 elements/thread.
__global__ __launch_bounds__(256) void vscale_kernel(
        const float* __restrict__ V, const float* __restrict__ mask,
        short* __restrict__ Vb) {
    size_t e = ((size_t)blockIdx.x * 256 + threadIdx.x) * 8;
    int b = (int)(e >> 19);            // C_*L_ = 2^19
    int m = (int)(e & (L_ - 1));
    const float4 v0 = *(const float4*)(V + e);
    const float4 v1 = *(const float4*)(V + e + 4);
    const float* mp = mask + ((size_t)b << 11) + m;
    const float4 m0 = *(const float4*)mp;
    const float4 m1 = *(const float4*)(mp + 4);
    unsigned o0 = (unsigned)(unsigned short)f2bf_rne(v0.x * m0.x)
                | ((unsigned)(unsigned short)f2bf_rne(v0.y * m0.y) << 16);
    unsigned o1 = (unsigned)(unsigned short)f2bf_rne(v0.z * m0.z)
                | ((unsigned)(unsigned short)f2bf_rne(v0.w * m0.w) << 16);
    unsigned o2 = (unsigned)(unsigned short)f2bf_rne(v1.x * m1.x)
                | ((unsigned)(unsigned short)f2bf_rne(v1.y * m1.y) << 16);
    unsigned o3 = (unsigned)(unsigned short)f2bf_rne(v1.z * m1.z)
                | ((unsigned)(unsigned short)f2bf_rne(v1.w * m1.w) << 16);
    uint4 o; o.x = o0; o.y = o1; o.z = o2; o.w = o3;
    *(uint4*)(Vb + e) = o;
}

// ---------------- main fused attention ----------------
// grid = 512 (b = bid & 15 -> batch-per-XCD L2 locality; lt = bid >> 4), 256 threads = 4 waves.
// Each wg: 64 query rows (wave w owns rows 16w..16w+15). Loop over 64-wide m tiles.
__global__ __launch_bounds__(256, 2) void attn_main(
        const short* __restrict__ Qt,   // [B][L][C] bf16
        const short* __restrict__ Kt,   // [B][L][C] bf16 (rows are m)
        const short* __restrict__ Vb,   // [B][C][L] bf16, mask-scaled
        const float* __restrict__ mask, // [B][L]
        float* __restrict__ out) {      // [B][C][L]
    __shared__ __align__(16) char smem[73728];
    short* KsS = (short*)smem;              // [64][256] bf16, 16B-chunk XOR swizzle, 32KB
    short* VsS = (short*)(smem + 32768);    // [256][64] bf16, swizzled, 32KB
    short* PsS = (short*)(smem + 65536);    // 4 waves x [16][64] bf16, swizzled, 8KB

    const int t = threadIdx.x;
    const int w = t >> 6;
    const int lane = t & 63;
    const int q = lane >> 4;
    const int n = lane & 15;

    const int bid = blockIdx.x;
    const int b  = bid & 15;
    const int l0 = (bid >> 4) * 64;

    // preload Q A-fragments (loop-invariant): A[row=n][k=32ks+8q+j]
    bf16x8 qf[8];
    {
        const short* qrow = Qt + ((size_t)b * L_ + (l0 + 16 * w + n)) * C_;
        #pragma unroll
        for (int ks = 0; ks < 8; ++ks)
            qf[ks] = *(const bf16x8*)(qrow + 32 * ks + 8 * q);
    }

    const f32x4 fzero = {0.f, 0.f, 0.f, 0.f};
    f32x4 Oacc[16];
    #pragma unroll
    for (int i = 0; i < 16; ++i) Oacc[i] = fzero;
    float denom[4] = {0.f, 0.f, 0.f, 0.f};

    const short* Ksrc = Kt + (size_t)b * L_ * C_;
    const short* Vsrc = Vb + (size_t)b * C_ * L_;
    const float* mrow = mask + (size_t)b * L_;
    short* Pw = PsS + w * 1024;   // this wave's 16x64 P tile

    for (int m0 = 0; m0 < L_; m0 += 64) {
        // ---- stage K tile rows m0..m0+63 (all 256 c), 16B chunks, swizzle pc = kc ^ (m&31)
        #pragma unroll
        for (int g0 = 0; g0 < 2048; g0 += 256) {
            int g = g0 + t;
            int m = g >> 5, kc = g & 31;
            uint4 v = *(const uint4*)(Ksrc + (size_t)(m0 + m) * C_ + kc * 8);
            int pc = kc ^ (m & 31);
            *(uint4*)(KsS + m * 256 + pc * 8) = v;
        }
        // ---- stage V tile cols m0..m0+63 (all 256 c), swizzle pc = kc ^ (c&7)
        #pragma unroll
        for (int g0 = 0; g0 < 2048; g0 += 256) {
            int g = g0 + t;
            int c = g >> 3, kc = g & 7;
            uint4 v = *(const uint4*)(Vsrc + (size_t)c * L_ + m0 + kc * 8);
            int pc = kc ^ (c & 7);
            *(uint4*)(VsS + c * 64 + pc * 8) = v;
        }
        // per-lane mask weights for this tile's columns
        float wv[4];
        #pragma unroll
        for (int nt = 0; nt < 4; ++nt)
            wv[nt] = mrow[m0 + 16 * nt + n] + 1e-9f;

        __syncthreads();

        // ---- S = Q^T K : wave rows 16w.., cols m0 + 16nt + n
        f32x4 Sacc[4];
        #pragma unroll
        for (int nt = 0; nt < 4; ++nt) Sacc[nt] = fzero;
        #pragma unroll
        for (int ks = 0; ks < 8; ++ks) {
            #pragma unroll
            for (int nt = 0; nt < 4; ++nt) {
                int row = 16 * nt + n;
                int pc = (4 * ks + q) ^ (row & 31);
                bf16x8 bf = *(const bf16x8*)(KsS + row * 256 + pc * 8);
                Sacc[nt] = __builtin_amdgcn_mfma_f32_16x16x32_bf16(qf[ks], bf, Sacc[nt], 0, 0, 0);
            }
        }

        // ---- P = w * exp(S/16); accumulate denom; write P (C-layout -> A-layout via LDS)
        #pragma unroll
        for (int nt = 0; nt < 4; ++nt) {
            int m = 16 * nt + n;
            #pragma unroll
            for (int r = 0; r < 4; ++r) {
                float p = wv[nt] * __expf(Sacc[nt][r] * 0.0625f);
                denom[r] += p;
                int l = 4 * q + r;
                int pe = (((m >> 3) ^ (l & 7)) << 3) | (m & 7);
                Pw[l * 64 + pe] = f2bf_rne(p);
            }
        }
        // per-wave LDS region: no barrier needed (compiler orders via lgkmcnt)

        // ---- O += P * Vb^T : A-frags from Pw, B-frags from Vs
        bf16x8 af[2];
        #pragma unroll
        for (int ks2 = 0; ks2 < 2; ++ks2) {
            int pc = (4 * ks2 + q) ^ (n & 7);
            af[ks2] = *(const bf16x8*)(Pw + n * 64 + pc * 8);
        }
        #pragma unroll
        for (int nt2 = 0; nt2 < 16; ++nt2) {
            int c = 16 * nt2 + n;
            #pragma unroll
            for (int ks2 = 0; ks2 < 2; ++ks2) {
                int pc = (4 * ks2 + q) ^ (n & 7);
                bf16x8 vf = *(const bf16x8*)(VsS + c * 64 + pc * 8);
                Oacc[nt2] = __builtin_amdgcn_mfma_f32_16x16x32_bf16(af[ks2], vf, Oacc[nt2], 0, 0, 0);
            }
        }
        __syncthreads();   // protect Ks/Vs before next stage (and before epilogue alias)
    }

    // ---- epilogue: finish denom (reduce over the 16 column-lanes), normalize, transpose, store
    #pragma unroll
    for (int d = 1; d < 16; d <<= 1) {
        #pragma unroll
        for (int r = 0; r < 4; ++r)
            denom[r] += __shfl_xor(denom[r], d, 64);
    }
    float rden[4];
    #pragma unroll
    for (int r = 0; r < 4; ++r) rden[r] = 1.0f / denom[r];

    float* Osh = (float*)smem;   // [256][65] fp32, 66.5KB (aliases Ks/Vs/Ps; safe after barrier)
    #pragma unroll
    for (int nt2 = 0; nt2 < 16; ++nt2) {
        int c = 16 * nt2 + n;
        #pragma unroll
        for (int r = 0; r < 4; ++r) {
            int l = 16 * w + 4 * q + r;
            Osh[c * 65 + l] = Oacc[nt2][r] * rden[r];
        }
    }
    __syncthreads();
    float* orow = out + (size_t)b * C_ * L_ + l0;
    #pragma unroll 8
    for (int i = 0; i < 64; ++i) {
        int c = 64 * w + i;
        orow[(size_t)c * L_ + lane] = Osh[c * 65 + lane];   // 256B coalesced stores
    }
}

extern "C" void kernel_launch(void* const* d_in, const int* in_sizes, int n_in,
                              void* d_out, int out_size, void* d_ws, size_t ws_size,
                              hipStream_t stream) {
    const float* Q    = (const float*)d_in[0];
    const float* K    = (const float*)d_in[1];
    const float* V    = (const float*)d_in[2];
    const float* mask = (const float*)d_in[3];
    float* out = (float*)d_out;

    // workspace layout: Qt | Kt | Vb, each B*L*C bf16 = 16 MiB -> 48 MiB total
    short* Qt = (short*)d_ws;
    short* Kt = Qt + (size_t)B_ * L_ * C_;
    short* Vb = Kt + (size_t)B_ * L_ * C_;

    transpose_cvt_kernel<<<4096, 256, 0, stream>>>(Q, K, Qt, Kt);
    vscale_kernel<<<4096, 256, 0, stream>>>(V, mask, Vb);
    attn_main<<<512, 256, 0, stream>>>(Qt, Kt, Vb, mask, out);
}

// Round 3
// 244.171 us; speedup vs baseline: 1.4393x; 1.4393x over previous
//
#include <hip/hip_runtime.h>
#include <hip/hip_bf16.h>

#define B_ 16
#define C_ 256
#define L_ 2048
#define MT 32   // m-tile per iteration

typedef __attribute__((ext_vector_type(8))) short bf16x8;
typedef __attribute__((ext_vector_type(4))) float f32x4;

// round-to-nearest-even float -> bf16
__device__ __forceinline__ short f2bf_rne(float f) {
    union { float f; unsigned u; } x; x.f = f;
    unsigned r = x.u + 0x7fffu + ((x.u >> 16) & 1u);
    return (short)(r >> 16);
}

// direct global->LDS DMA, 16 bytes per lane. LDS side is wave-uniform base + lane*16.
__device__ __forceinline__ void gld_lds16(const void* g, void* l) {
    __builtin_amdgcn_global_load_lds(
        (const __attribute__((address_space(1))) void*)g,
        (__attribute__((address_space(3))) void*)l, 16, 0, 0);
}

// ---------------- fused prepass: Q/K transpose+cvt (blocks 0..4095), V*mask cvt (4096..8191) ----
__global__ __launch_bounds__(256) void prepass_kernel(
        const float* __restrict__ Qin, const float* __restrict__ Kin,
        const float* __restrict__ Vin, const float* __restrict__ mask,
        short* __restrict__ Qt, short* __restrict__ Kt, short* __restrict__ Vb) {
    const int bid = blockIdx.x;
    const int t = threadIdx.x;
    if (bid < 4096) {
        __shared__ unsigned short tile[64 * 65];   // [li][ci]
        const int tens = bid >> 11;
        const int b  = (bid >> 7) & 15;
        const int c0 = ((bid >> 5) & 3) * 64;
        const int l0 = (bid & 31) * 64;
        const float* __restrict__ src = tens ? Kin : Qin;
        short* __restrict__ dst = tens ? Kt : Qt;
        #pragma unroll
        for (int i = 0; i < 4; ++i) {
            int idx = i * 256 + t;                 // 0..1023
            int ci = idx >> 4;                     // 0..63
            int lc = (idx & 15) * 4;               // l-chunk of 4
            float4 v = *(const float4*)(src + ((size_t)b * C_ + (c0 + ci)) * L_ + l0 + lc);
            tile[(lc + 0) * 65 + ci] = (unsigned short)f2bf_rne(v.x);
            tile[(lc + 1) * 65 + ci] = (unsigned short)f2bf_rne(v.y);
            tile[(lc + 2) * 65 + ci] = (unsigned short)f2bf_rne(v.z);
            tile[(lc + 3) * 65 + ci] = (unsigned short)f2bf_rne(v.w);
        }
        __syncthreads();
        #pragma unroll
        for (int i = 0; i < 8; ++i) {
            int li = 8 * i + (t >> 5);
            int cp = (t & 31) * 2;
            unsigned lo = tile[li * 65 + cp];
            unsigned hi = tile[li * 65 + cp + 1];
            *(unsigned*)(dst + ((size_t)b * L_ + (l0 + li)) * C_ + c0 + cp) = lo | (hi << 16);
        }
    } else {
        // 4096 blocks x 256 threads x 8 elems = B_*C_*L_ exactly
        size_t e = ((size_t)(bid - 4096) * 256 + t) * 8;
        int b = (int)(e >> 19);
        int m = (int)(e & (L_ - 1));
        const float4 v0 = *(const float4*)(Vin + e);
        const float4 v1 = *(const float4*)(Vin + e + 4);
        const float* mp = mask + ((size_t)b << 11) + m;
        const float4 m0 = *(const float4*)mp;
        const float4 m1 = *(const float4*)(mp + 4);
        uint4 o;
        o.x = (unsigned)(unsigned short)f2bf_rne(v0.x * m0.x)
            | ((unsigned)(unsigned short)f2bf_rne(v0.y * m0.y) << 16);
        o.y = (unsigned)(unsigned short)f2bf_rne(v0.z * m0.z)
            | ((unsigned)(unsigned short)f2bf_rne(v0.w * m0.w) << 16);
        o.z = (unsigned)(unsigned short)f2bf_rne(v1.x * m1.x)
            | ((unsigned)(unsigned short)f2bf_rne(v1.y * m1.y) << 16);
        o.w = (unsigned)(unsigned short)f2bf_rne(v1.z * m1.z)
            | ((unsigned)(unsigned short)f2bf_rne(v1.w * m1.w) << 16);
        *(uint4*)(Vb + e) = o;
    }
}

// ---- stage one 32-row K tile + 32-col V tile via DMA; XOR swizzle on the GLOBAL side ----
// K LDS layout: [m 0..31][slot 0..31 of 16B]; physical slot p holds global chunk kc = p ^ m.
// V LDS layout: [c 0..255][slot 0..3 of 16B];  physical slot p holds global chunk kc = p ^ (c&3).
__device__ __forceinline__ void stage_tiles(const short* __restrict__ Ksrc,
                                            const short* __restrict__ Vsrc,
                                            short* Ks, short* Vs, int m0, int t) {
    #pragma unroll
    for (int rr = 0; rr < 4; ++rr) {
        int G = rr * 256 + t;                  // chunk index 0..1023
        int m = G >> 5, p = G & 31;
        int kc = p ^ m;
        gld_lds16(Ksrc + ((size_t)(m0 + m) << 8) + kc * 8, Ks + G * 8);
    }
    #pragma unroll
    for (int rr = 0; rr < 4; ++rr) {
        int G = rr * 256 + t;
        int c = G >> 2, p = G & 3;
        int kc = p ^ (c & 3);
        gld_lds16(Vsrc + (size_t)c * L_ + m0 + kc * 8, Vs + G * 8);
    }
}

// ---------------- main fused attention (double-buffered DMA pipeline) ----------------
// 512 blocks (b = bid&15, l0 = (bid>>4)*64), 4 waves; wave owns 16 query rows.
__global__ __launch_bounds__(256, 2) void attn_main(
        const short* __restrict__ Qt,   // [B][L][C] bf16
        const short* __restrict__ Kt,   // [B][L][C] bf16
        const short* __restrict__ Vb,   // [B][C][L] bf16, mask-scaled
        const float* __restrict__ mask, // [B][L]
        float* __restrict__ out) {      // [B][C][L]
    __shared__ __align__(16) char smem[70656];
    short* KsB0 = (short*)smem;                 // 16 KB
    short* KsB1 = (short*)(smem + 16384);       // 16 KB
    short* VsB0 = (short*)(smem + 32768);       // 16 KB
    short* VsB1 = (short*)(smem + 49152);       // 16 KB
    // P: per wave 16 rows x 80 B (32 bf16 + 16 B pad) = 1280 B -> 5 KB
    const int t = threadIdx.x;
    const int w = t >> 6, lane = t & 63, q = lane >> 4, n = lane & 15;
    short* Pw = (short*)(smem + 65536) + w * 640;

    const int b  = blockIdx.x & 15;
    const int l0 = (blockIdx.x >> 4) * 64;

    // loop-invariant Q A-fragments: A[row=n][k=32ks+8q+j]
    bf16x8 qf[8];
    {
        const short* qrow = Qt + ((size_t)b * L_ + (l0 + 16 * w + n)) * C_;
        #pragma unroll
        for (int ks = 0; ks < 8; ++ks)
            qf[ks] = *(const bf16x8*)(qrow + 32 * ks + 8 * q);
    }

    const f32x4 fzero = {0.f, 0.f, 0.f, 0.f};
    f32x4 Oacc[16];
    #pragma unroll
    for (int i = 0; i < 16; ++i) Oacc[i] = fzero;
    float denom[4] = {0.f, 0.f, 0.f, 0.f};

    const short* Ksrc = Kt + (size_t)b * L_ * C_;
    const short* Vsrc = Vb + (size_t)b * C_ * L_;
    const float* mrow = mask + (size_t)b * L_;

    // prologue: stage tile 0 into buffer 0; prefetch first mask values
    stage_tiles(Ksrc, Vsrc, KsB0, VsB0, 0, t);
    float wva = mrow[n] + 1e-9f;
    float wvb = mrow[16 + n] + 1e-9f;

    const float CEXP = 0.09016844005556021f;  // (1/16) * log2(e)

    for (int it = 0; it < L_ / MT; ++it) {
        const int cur = it & 1;
        const short* Ks = cur ? KsB1 : KsB0;
        const short* Vs = cur ? VsB1 : VsB0;

        __syncthreads();   // drains DMA: buf[cur] staged; buf[!cur] free to overwrite

        float nwa = 0.f, nwb = 0.f;
        if (it + 1 < L_ / MT) {
            // issue next tile's DMAs into the other buffer; they overlap this compute
            stage_tiles(Ksrc, Vsrc, cur ? KsB0 : KsB1, cur ? VsB0 : VsB1, (it + 1) * MT, t);
            nwa = mrow[(it + 1) * MT + n] + 1e-9f;
            nwb = mrow[(it + 1) * MT + 16 + n] + 1e-9f;
        }

        // ---- S = Q K^T for this wave's 16 rows x 32 cols
        f32x4 S0 = fzero, S1 = fzero;
        #pragma unroll
        for (int ks = 0; ks < 8; ++ks) {
            int kq = 4 * ks + q;
            bf16x8 b0 = *(const bf16x8*)(Ks + n * 256 + (kq ^ n) * 8);
            S0 = __builtin_amdgcn_mfma_f32_16x16x32_bf16(qf[ks], b0, S0, 0, 0, 0);
            bf16x8 b1 = *(const bf16x8*)(Ks + (16 + n) * 256 + (kq ^ (16 + n)) * 8);
            S1 = __builtin_amdgcn_mfma_f32_16x16x32_bf16(qf[ks], b1, S1, 0, 0, 0);
        }

        // ---- P = w*exp(S/16), accumulate denom, write P (C-layout -> A-layout, padded rows)
        #pragma unroll
        for (int r = 0; r < 4; ++r) {
            int l = 4 * q + r;
            float p0 = wva * exp2f(S0[r] * CEXP);
            denom[r] += p0;
            Pw[l * 40 + (n >> 3) * 8 + (n & 7)] = f2bf_rne(p0);        // m = n
            float p1 = wvb * exp2f(S1[r] * CEXP);
            denom[r] += p1;
            Pw[l * 40 + (2 + (n >> 3)) * 8 + (n & 7)] = f2bf_rne(p1);  // m = 16+n
        }

        // ---- O += P V^T (per-wave P region; same-wave LDS ops are ordered)
        bf16x8 af = *(const bf16x8*)(Pw + n * 40 + q * 8);   // A[row=n][k=8q+j]
        #pragma unroll
        for (int nt2 = 0; nt2 < 16; ++nt2) {
            int c = 16 * nt2 + n;
            bf16x8 vf = *(const bf16x8*)(Vs + c * 32 + (q ^ (c & 3)) * 8);
            Oacc[nt2] = __builtin_amdgcn_mfma_f32_16x16x32_bf16(af, vf, Oacc[nt2], 0, 0, 0);
        }

        wva = nwa; wvb = nwb;
    }

    __syncthreads();   // all waves done with K/V/P before aliasing smem

    // ---- epilogue: reduce denom over the 16 column-lanes, normalize, transpose, store
    #pragma unroll
    for (int d = 1; d < 16; d <<= 1) {
        #pragma unroll
        for (int r = 0; r < 4; ++r)
            denom[r] += __shfl_xor(denom[r], d, 64);
    }
    float rden[4];
    #pragma unroll
    for (int r = 0; r < 4; ++r) rden[r] = 1.0f / denom[r];

    float* Osh = (float*)smem;   // [256][65] fp32 = 66560 B (fits in 70656)
    #pragma unroll
    for (int nt2 = 0; nt2 < 16; ++nt2) {
        int c = 16 * nt2 + n;
        #pragma unroll
        for (int r = 0; r < 4; ++r) {
            int l = 16 * w + 4 * q + r;
            Osh[c * 65 + l] = Oacc[nt2][r] * rden[r];
        }
    }
    __syncthreads();
    float* orow = out + (size_t)b * C_ * L_ + l0;
    #pragma unroll 8
    for (int i = 0; i < 64; ++i) {
        int c = 64 * w + i;
        orow[(size_t)c * L_ + lane] = Osh[c * 65 + lane];
    }
}

extern "C" void kernel_launch(void* const* d_in, const int* in_sizes, int n_in,
                              void* d_out, int out_size, void* d_ws, size_t ws_size,
                              hipStream_t stream) {
    const float* Q    = (const float*)d_in[0];
    const float* K    = (const float*)d_in[1];
    const float* V    = (const float*)d_in[2];
    const float* mask = (const float*)d_in[3];
    float* out = (float*)d_out;

    short* Qt = (short*)d_ws;
    short* Kt = Qt + (size_t)B_ * L_ * C_;
    short* Vb = Kt + (size_t)B_ * L_ * C_;

    prepass_kernel<<<8192, 256, 0, stream>>>(Q, K, V, mask, Qt, Kt, Vb);
    attn_main<<<512, 256, 0, stream>>>(Qt, Kt, Vb, mask, out);
}

// Round 4
// 231.566 us; speedup vs baseline: 1.5177x; 1.0544x over previous
//
#include <hip/hip_runtime.h>
#include <hip/hip_bf16.h>

#define B_ 16
#define C_ 256
#define L_ 2048
#define MT 32   // m-tile per iteration

typedef __attribute__((ext_vector_type(8))) short bf16x8;
typedef __attribute__((ext_vector_type(4))) float f32x4;

#define CEXP 0.09016844005556021f   // (1/16) * log2(e), folded into Q at prepass

// round-to-nearest-even float -> bf16
__device__ __forceinline__ short f2bf_rne(float f) {
    union { float f; unsigned u; } x; x.f = f;
    unsigned r = x.u + 0x7fffu + ((x.u >> 16) & 1u);
    return (short)(r >> 16);
}

// direct global->LDS DMA, 16 bytes per lane; LDS dest = wave-uniform base + lane*16
__device__ __forceinline__ void gld_lds16(const void* g, void* l) {
    __builtin_amdgcn_global_load_lds(
        (const __attribute__((address_space(1))) void*)g,
        (__attribute__((address_space(3))) void*)l, 16, 0, 0);
}

// barrier that waits LDS ops only (lgkmcnt(0)), leaving DMA (vmcnt) in flight.
// 0xC07F = vmcnt 63 (bits 3:0 + 15:14), expcnt 7, lgkmcnt 0.
__device__ __forceinline__ void barrier_lds_only() {
    asm volatile("" ::: "memory");
    __builtin_amdgcn_s_waitcnt(0xC07F);
    __builtin_amdgcn_s_barrier();
    asm volatile("" ::: "memory");
}

// ---------------- prepass: Q/K transpose+cvt (blocks 0..1023), V*mask cvt (1024..5119) ----
// Transpose: block = (tensor, b, 64-l strip). LDS tile [l][32 chunks of 16B], chunk XOR-swizzled.
// Output written as full 512-B bf16 rows (fully coalesced). Q additionally scaled by CEXP.
__global__ __launch_bounds__(256) void prepass_kernel(
        const float* __restrict__ Qin, const float* __restrict__ Kin,
        const float* __restrict__ Vin, const float* __restrict__ mask,
        short* __restrict__ Qt, short* __restrict__ Kt, short* __restrict__ Vb) {
    const int bid = blockIdx.x;
    const int t = threadIdx.x;
    if (bid < 1024) {
        __shared__ unsigned short tile[64 * 256];   // 32 KB, phys chunk = (c>>3) ^ (l&31)
        const int tens = bid >> 9;
        const int b  = (bid >> 5) & 15;
        const int l0 = (bid & 31) * 64;
        const float* __restrict__ src = tens ? Kin : Qin;
        short* __restrict__ dst = tens ? Kt : Qt;
        const float scale = tens ? 1.0f : CEXP;
        #pragma unroll
        for (int iter = 0; iter < 16; ++iter) {
            int idx = iter * 256 + t;              // 0..4095
            int ci = idx >> 4;                     // 0..255
            int lc = (idx & 15) * 4;               // l-chunk of 4
            float4 v = *(const float4*)(src + ((size_t)(b * C_ + ci)) * L_ + l0 + lc);
            float vv[4] = {v.x, v.y, v.z, v.w};
            #pragma unroll
            for (int j = 0; j < 4; ++j) {
                int l = lc + j;
                tile[l * 256 + (((ci >> 3) ^ (l & 31)) << 3) + (ci & 7)] =
                    (unsigned short)f2bf_rne(vv[j] * scale);
            }
        }
        __syncthreads();
        #pragma unroll
        for (int iter = 0; iter < 8; ++iter) {
            int li = iter * 8 + (t >> 5);          // 0..63
            int ck = t & 31;                       // logical 16-B chunk
            uint4 val = *(const uint4*)(tile + li * 256 + ((ck ^ (li & 31)) << 3));
            *(uint4*)(dst + ((size_t)(b * L_ + l0 + li)) * C_ + ck * 8) = val;
        }
    } else {
        // 4096 blocks x 256 threads x 8 elems = B_*C_*L_
        size_t e = ((size_t)(bid - 1024) * 256 + t) * 8;
        int b = (int)(e >> 19);
        int m = (int)(e & (L_ - 1));
        const float4 v0 = *(const float4*)(Vin + e);
        const float4 v1 = *(const float4*)(Vin + e + 4);
        const float* mp = mask + ((size_t)b << 11) + m;
        const float4 m0 = *(const float4*)mp;
        const float4 m1 = *(const float4*)(mp + 4);
        uint4 o;
        o.x = (unsigned)(unsigned short)f2bf_rne(v0.x * m0.x)
            | ((unsigned)(unsigned short)f2bf_rne(v0.y * m0.y) << 16);
        o.y = (unsigned)(unsigned short)f2bf_rne(v0.z * m0.z)
            | ((unsigned)(unsigned short)f2bf_rne(v0.w * m0.w) << 16);
        o.z = (unsigned)(unsigned short)f2bf_rne(v1.x * m1.x)
            | ((unsigned)(unsigned short)f2bf_rne(v1.y * m1.y) << 16);
        o.w = (unsigned)(unsigned short)f2bf_rne(v1.z * m1.z)
            | ((unsigned)(unsigned short)f2bf_rne(v1.w * m1.w) << 16);
        *(uint4*)(Vb + e) = o;
    }
}

// ---- stage one 32-row K tile + 32-col V tile via DMA; XOR swizzle on the GLOBAL side ----
// K: [m 0..31][slot p 0..31]; p holds global chunk kc = p ^ m.          (reads verified <=2-way)
// V: [c 0..255][slot p 0..3];  p holds global chunk kc = p ^ ((c>>1)&3). (reads verified <=2-way)
__device__ __forceinline__ void stage_tiles(const short* __restrict__ Ksrc,
                                            const short* __restrict__ Vsrc,
                                            short* Ks, short* Vs, int m0, int t) {
    #pragma unroll
    for (int rr = 0; rr < 4; ++rr) {
        int G = rr * 256 + t;                  // 0..1023
        int m = G >> 5, p = G & 31;
        gld_lds16(Ksrc + ((size_t)(m0 + m) << 8) + (p ^ m) * 8, Ks + G * 8);
    }
    #pragma unroll
    for (int rr = 0; rr < 4; ++rr) {
        int G = rr * 256 + t;
        int c = G >> 2, p = G & 3;
        int kc = (p ^ (c >> 1)) & 3;
        gld_lds16(Vsrc + (size_t)c * L_ + m0 + kc * 8, Vs + G * 8);
    }
}

// ---------------- main fused attention ----------------
// 512 blocks (b = bid&15, l0 = (bid>>4)*64), 4 waves.
// S-phase: wave (g = w&1, mt = w>>1) computes S rows 32g..32g+31 x cols 16mt..16mt+15.
// O-phase: wave w computes O cols c in [64w, 64w+64) x all 64 l (4x4 tile grid, frag reuse).
__global__ __launch_bounds__(256, 2) void attn_main(
        const short* __restrict__ Qt,   // [B][L][C] bf16 (pre-scaled by CEXP)
        const short* __restrict__ Kt,   // [B][L][C] bf16
        const short* __restrict__ Vb,   // [B][C][L] bf16, mask-scaled
        const float* __restrict__ mask, // [B][L]
        float* __restrict__ out) {      // [B][C][L]
    __shared__ __align__(16) char smem[71168];
    short* KsB0 = (short*)smem;                 // 16 KB
    short* KsB1 = (short*)(smem + 16384);
    short* VsB0 = (short*)(smem + 32768);
    short* VsB1 = (short*)(smem + 49152);
    short* Pl   = (short*)(smem + 65536);       // [64 l][40 shorts] = 5120 B (32 m + pad)
    float* Dsh  = (float*)(smem + 70656);       // [2][64] partial denoms, 512 B

    const int t = threadIdx.x;
    const int w = t >> 6, lane = t & 63, q = lane >> 4, n = lane & 15;
    const int g = w & 1, mt = w >> 1;

    const int b  = blockIdx.x & 15;
    const int l0 = (blockIdx.x >> 4) * 64;

    // loop-invariant Q A-frags for rows 32g + 16lt + n: A[row][k=32ks+8q+j]
    bf16x8 qf[2][8];
    {
        const short* qbase = Qt + ((size_t)b * L_ + (l0 + 32 * g)) * C_;
        #pragma unroll
        for (int lt = 0; lt < 2; ++lt)
            #pragma unroll
            for (int ks = 0; ks < 8; ++ks)
                qf[lt][ks] = *(const bf16x8*)(qbase + (size_t)(16 * lt + n) * C_ + 32 * ks + 8 * q);
    }

    const f32x4 fzero = {0.f, 0.f, 0.f, 0.f};
    f32x4 Oacc[4][4];
    #pragma unroll
    for (int i = 0; i < 4; ++i)
        #pragma unroll
        for (int j = 0; j < 4; ++j) Oacc[i][j] = fzero;
    float dn[2][4] = {{0.f,0.f,0.f,0.f},{0.f,0.f,0.f,0.f}};

    const short* Ksrc = Kt + (size_t)b * (L_ * C_);
    const short* Vsrc = Vb + (size_t)b * (C_ * L_);
    const float* mrow = mask + (size_t)b * L_;

    stage_tiles(Ksrc, Vsrc, KsB0, VsB0, 0, t);
    float wv = mrow[16 * mt + n] + 1e-9f;

    for (int it = 0; it < L_ / MT; ++it) {
        const int cur = it & 1;
        const short* Ks = cur ? KsB1 : KsB0;
        const short* Vs = cur ? VsB1 : VsB0;

        __syncthreads();   // buf[cur] DMA drained; prev O-phase complete

        float nw = 0.f;
        if (it + 1 < L_ / MT) {
            stage_tiles(Ksrc, Vsrc, cur ? KsB0 : KsB1, cur ? VsB0 : VsB1, (it + 1) * MT, t);
            nw = mrow[(it + 1) * MT + 16 * mt + n] + 1e-9f;
        }

        // ---- S: rows 32g+16lt+4q+r, col m = 16mt+n. 8 B-frag reads, 16 MFMA.
        const short* Krow = Ks + (16 * mt + n) * 256;
        f32x4 S0 = fzero, S1 = fzero;
        #pragma unroll
        for (int ks = 0; ks < 8; ++ks) {
            bf16x8 bf = *(const bf16x8*)(Krow + (((4 * ks + q) ^ (16 * mt + n)) << 3));
            S0 = __builtin_amdgcn_mfma_f32_16x16x32_bf16(qf[0][ks], bf, S0, 0, 0, 0);
            S1 = __builtin_amdgcn_mfma_f32_16x16x32_bf16(qf[1][ks], bf, S1, 0, 0, 0);
        }

        // ---- P = wv*exp2(S) (CEXP pre-folded into Q), accumulate denom, write P
        {
            short* Pb = Pl + (32 * g + 4 * q) * 40 + 16 * mt + n;
            #pragma unroll
            for (int r = 0; r < 4; ++r) {
                float p0 = wv * exp2f(S0[r]);
                dn[0][r] += p0;
                Pb[r * 40] = f2bf_rne(p0);
                float p1 = wv * exp2f(S1[r]);
                dn[1][r] += p1;
                Pb[(16 * 40) + r * 40] = f2bf_rne(p1);
            }
        }

        barrier_lds_only();   // P visible to all waves; DMA stays in flight

        // ---- O += P V^T: 4 A-frags + 4 B-frags for 16 MFMA
        bf16x8 af[4];
        #pragma unroll
        for (int lt = 0; lt < 4; ++lt)
            af[lt] = *(const bf16x8*)(Pl + (16 * lt + n) * 40 + q * 8);
        #pragma unroll
        for (int ct = 0; ct < 4; ++ct) {
            int c = 64 * w + 16 * ct + n;
            bf16x8 vf = *(const bf16x8*)(Vs + c * 32 + (((q ^ (c >> 1)) & 3) << 3));
            #pragma unroll
            for (int lt = 0; lt < 4; ++lt)
                Oacc[lt][ct] = __builtin_amdgcn_mfma_f32_16x16x32_bf16(af[lt], vf, Oacc[lt][ct], 0, 0, 0);
        }

        wv = nw;
    }

    __syncthreads();

    // ---- denom: reduce over 16 n-lanes, combine mt halves via LDS
    #pragma unroll
    for (int d = 1; d < 16; d <<= 1) {
        #pragma unroll
        for (int lt = 0; lt < 2; ++lt)
            #pragma unroll
            for (int r = 0; r < 4; ++r)
                dn[lt][r] += __shfl_xor(dn[lt][r], d, 64);
    }
    if (n == 0) {
        #pragma unroll
        for (int lt = 0; lt < 2; ++lt)
            #pragma unroll
            for (int r = 0; r < 4; ++r)
                Dsh[mt * 64 + 32 * g + 16 * lt + 4 * q + r] = dn[lt][r];
    }
    __syncthreads();

    float rden[4][4];
    #pragma unroll
    for (int lt = 0; lt < 4; ++lt)
        #pragma unroll
        for (int r = 0; r < 4; ++r) {
            int l = 16 * lt + 4 * q + r;
            rden[lt][r] = 1.0f / (Dsh[l] + Dsh[64 + l]);
        }

    // ---- normalize + transpose through LDS, coalesced 256-B stores
    float* Osh = (float*)smem;   // [256][65] fp32 = 66560 B (aliases K/V/P; Dsh untouched)
    #pragma unroll
    for (int lt = 0; lt < 4; ++lt)
        #pragma unroll
        for (int ct = 0; ct < 4; ++ct) {
            int c = 64 * w + 16 * ct + n;
            #pragma unroll
            for (int r = 0; r < 4; ++r)
                Osh[c * 65 + 16 * lt + 4 * q + r] = Oacc[lt][ct][r] * rden[lt][r];
        }
    __syncthreads();
    float* orow = out + (size_t)b * (C_ * L_) + l0;
    #pragma unroll 8
    for (int i = 0; i < 64; ++i) {
        int c = 64 * w + i;
        orow[(size_t)c * L_ + lane] = Osh[c * 65 + lane];
    }
}

extern "C" void kernel_launch(void* const* d_in, const int* in_sizes, int n_in,
                              void* d_out, int out_size, void* d_ws, size_t ws_size,
                              hipStream_t stream) {
    const float* Q    = (const float*)d_in[0];
    const float* K    = (const float*)d_in[1];
    const float* V    = (const float*)d_in[2];
    const float* mask = (const float*)d_in[3];
    float* out = (float*)d_out;

    short* Qt = (short*)d_ws;
    short* Kt = Qt + (size_t)B_ * L_ * C_;
    short* Vb = Kt + (size_t)B_ * L_ * C_;

    prepass_kernel<<<5120, 256, 0, stream>>>(Q, K, V, mask, Qt, Kt, Vb);
    attn_main<<<512, 256, 0, stream>>>(Qt, Kt, Vb, mask, out);
}